// Round 1
// baseline (4178.105 us; speedup 1.0000x reference)
//
#include <hip/hip_runtime.h>
#include <math.h>

#define D 128
#define DH 32
#define RG 4
#define BLOCKS_AC 768
#define THREADS_AC 256

__device__ __forceinline__ float fast_tanh(float z) {
    float e = __expf(2.f * z);
    return 1.f - 2.f / (e + 1.f);
}

// PHASE 0: compute x2, accumulate segment sums + counts.
// PHASE 1: recompute x2, coef = sigmoid(x2 . tg[batch]), accumulate coef*x2 into out.
template <int PHASE>
__global__ __launch_bounds__(THREADS_AC, 3) void phaseAC(
    const float* __restrict__ x, const int* __restrict__ batch,
    const float* __restrict__ fc1_w, const float* __restrict__ fc1_b,
    const float* __restrict__ fc2_w, const float* __restrict__ fc2_b,
    const float* __restrict__ tg, float* __restrict__ dst,
    float* __restrict__ cnt, int N)
{
    __shared__ float W1s[DH][D + 4];   // pitch 132: 16B-aligned rows, spread banks
    __shared__ float W2s[DH][D];       // [j][d] so lanes read consecutive d
    __shared__ float xs[4][RG * D];    // per-wave x rows
    __shared__ float hs[4][RG * DH];   // per-wave hidden acts

    for (int idx = threadIdx.x; idx < DH * D; idx += THREADS_AC) {
        int j = idx >> 7, k = idx & (D - 1);
        W1s[j][k] = fc1_w[idx];          // fc1_w [32][128] row-major
        W2s[j][k] = fc2_w[k * DH + j];   // fc2_w [128][32] -> transpose (k is 'd')
    }
    const int lane = threadIdx.x & 63;
    const int wv = threadIdx.x >> 6;
    const int jl = lane & 31;
    const int kb = (lane >> 5) << 6;   // half-wave: k in [0,64) or [64,128)
    const float b1r = fc1_b[jl];
    const float b20 = fc2_b[lane];
    const float b21 = fc2_b[lane + 64];
    __syncthreads();

    int chunk = (N + (int)gridDim.x - 1) / (int)gridDim.x;
    int bs = blockIdx.x * chunk;
    int be = min(N, bs + chunk);
    int rows = be - bs; if (rows < 0) rows = 0;
    int wn = (rows + 3) >> 2;          // contiguous sub-range per wave
    int rs = bs + wv * wn;
    int re = min(be, rs + wn);

    float* xw = xs[wv];
    float* hw = hs[wv];

    float acc0 = 0.f, acc1 = 0.f, acnt = 0.f;
    int cur = -1;

    for (int r0 = rs; r0 < re; r0 += RG) {
        float x0[RG], x1[RG];
        #pragma unroll
        for (int g = 0; g < RG; ++g) {
            int r = r0 + g;
            if (r < re) {
                int base = r << 7;
                x0[g] = x[base + lane];
                x1[g] = x[base + 64 + lane];
            } else { x0[g] = 0.f; x1[g] = 0.f; }
            xw[g * D + lane] = x0[g];
            xw[g * D + 64 + lane] = x1[g];
        }
        // h = W1 x : lane jl computes h[jl] partial over its half of k
        float ha[RG] = {0.f, 0.f, 0.f, 0.f};
        #pragma unroll
        for (int kk = 0; kk < 64; kk += 4) {
            float4 w = *(const float4*)&W1s[jl][kb + kk];
            #pragma unroll
            for (int g = 0; g < RG; ++g) {
                float4 xv = *(const float4*)&xw[g * D + kb + kk];
                ha[g] = fmaf(w.x, xv.x, ha[g]);
                ha[g] = fmaf(w.y, xv.y, ha[g]);
                ha[g] = fmaf(w.z, xv.z, ha[g]);
                ha[g] = fmaf(w.w, xv.w, ha[g]);
            }
        }
        #pragma unroll
        for (int g = 0; g < RG; ++g) {
            float h = ha[g] + __shfl_xor(ha[g], 32);
            h = fmaxf(h + b1r, 0.f);
            if (lane < 32) hw[g * DH + jl] = h;
        }
        // a = W2 h : lane handles d = lane and lane+64
        float a0[RG] = {0.f,0.f,0.f,0.f}, a1[RG] = {0.f,0.f,0.f,0.f};
        #pragma unroll
        for (int jj = 0; jj < DH; jj += 4) {
            float4 hv[RG];
            #pragma unroll
            for (int g = 0; g < RG; ++g) hv[g] = *(const float4*)&hw[g * DH + jj];
            #pragma unroll
            for (int u = 0; u < 4; ++u) {
                float w0 = W2s[jj + u][lane];
                float w1 = W2s[jj + u][lane + 64];
                #pragma unroll
                for (int g = 0; g < RG; ++g) {
                    float hc = ((const float*)&hv[g])[u];
                    a0[g] = fmaf(w0, hc, a0[g]);
                    a1[g] = fmaf(w1, hc, a1[g]);
                }
            }
        }
        #pragma unroll
        for (int g = 0; g < RG; ++g) {
            int r = r0 + g;
            if (r >= re) break;                 // wave-uniform
            float t0 = fast_tanh(a0[g] + b20);
            float t1 = fast_tanh(a1[g] + b21);
            float y0 = fmaf(x0[g], t0, x0[g]);  // x*(1+tanh)
            float y1 = fmaf(x1[g], t1, x1[g]);
            int seg = batch[r];
            if (PHASE == 1) {
                float g0 = tg[(seg << 7) + lane];
                float g1 = tg[(seg << 7) + 64 + lane];
                float dot = y0 * g0 + y1 * g1;
                #pragma unroll
                for (int off = 32; off; off >>= 1) dot += __shfl_xor(dot, off);
                float coef = 1.f / (1.f + __expf(-dot));
                y0 *= coef; y1 *= coef;
            }
            if (seg != cur) {
                if (cur >= 0) {
                    atomicAdd(&dst[(cur << 7) + lane], acc0);
                    atomicAdd(&dst[(cur << 7) + 64 + lane], acc1);
                    if (PHASE == 0 && lane == 0) atomicAdd(&cnt[cur], acnt);
                }
                cur = seg; acc0 = y0; acc1 = y1; acnt = 1.f;
            } else {
                acc0 += y0; acc1 += y1; acnt += 1.f;
            }
        }
    }
    if (cur >= 0) {
        atomicAdd(&dst[(cur << 7) + lane], acc0);
        atomicAdd(&dst[(cur << 7) + 64 + lane], acc1);
        if (PHASE == 0 && lane == 0) atomicAdd(&cnt[cur], acnt);
    }
}

// tg = tanh((sums/max(cnt,1)) @ Wm), one block (128 thr) per segment row
__global__ __launch_bounds__(D, 8) void phaseB(
    const float* __restrict__ sums, const float* __restrict__ cnt,
    const float* __restrict__ Wm, float* __restrict__ tg)
{
    int b = blockIdx.x;
    int d = threadIdx.x;
    __shared__ float m[D];
    float inv = 1.f / fmaxf(cnt[b], 1.f);
    m[d] = sums[(b << 7) + d] * inv;
    __syncthreads();
    float acc = 0.f;
    #pragma unroll 8
    for (int k = 0; k < D; ++k)
        acc = fmaf(m[k], Wm[(k << 7) + d], acc);
    tg[(b << 7) + d] = fast_tanh(acc);
}

extern "C" void kernel_launch(void* const* d_in, const int* in_sizes, int n_in,
                              void* d_out, int out_size, void* d_ws, size_t ws_size,
                              hipStream_t stream) {
    const float* x     = (const float*)d_in[0];
    const int*   batch = (const int*)d_in[1];
    // d_in[2] = size scalar (B derived from out_size instead)
    const float* Wm    = (const float*)d_in[3];
    const float* fc1_w = (const float*)d_in[4];
    const float* fc1_b = (const float*)d_in[5];
    const float* fc2_w = (const float*)d_in[6];
    const float* fc2_b = (const float*)d_in[7];
    float* out = (float*)d_out;

    int N = in_sizes[0] / D;
    int B = out_size / D;

    float* sums = (float*)d_ws;          // [B,128]
    float* cnt  = sums + (size_t)B * D;  // [B]
    float* tg   = cnt + B;               // [B,128]

    hipMemsetAsync(d_ws, 0, ((size_t)B * D + B) * sizeof(float), stream);
    hipMemsetAsync(d_out, 0, (size_t)out_size * sizeof(float), stream);

    phaseAC<0><<<BLOCKS_AC, THREADS_AC, 0, stream>>>(
        x, batch, fc1_w, fc1_b, fc2_w, fc2_b, nullptr, sums, cnt, N);
    phaseB<<<B, D, 0, stream>>>(sums, cnt, Wm, tg);
    phaseAC<1><<<BLOCKS_AC, THREADS_AC, 0, stream>>>(
        x, batch, fc1_w, fc1_b, fc2_w, fc2_b, tg, out, nullptr, N);
}

// Round 2
// 4174.391 us; speedup vs baseline: 1.0009x; 1.0009x over previous
//
#include <hip/hip_runtime.h>
#include <math.h>

#define D 128
#define DH 32
#define RG 4
#define BLOCKS_AC 768
#define THREADS_AC 256

__device__ __forceinline__ float fast_tanh(float z) {
    float e = __expf(2.f * z);
    return 1.f - 2.f / (e + 1.f);
}

// PHASE 0: compute x2, accumulate segment sums + counts.
// PHASE 1: recompute x2, coef = sigmoid(x2 . tg[batch]), accumulate coef*x2 into out.
template <int PHASE>
__global__ __launch_bounds__(THREADS_AC, 3) void phaseAC(
    const float* __restrict__ x, const int* __restrict__ batch,
    const float* __restrict__ fc1_w, const float* __restrict__ fc1_b,
    const float* __restrict__ fc2_w, const float* __restrict__ fc2_b,
    const float* __restrict__ tg, float* __restrict__ dst,
    float* __restrict__ cnt, int N)
{
    __shared__ float W1s[DH][D + 4];   // pitch 132: 16B-aligned rows, spread banks
    __shared__ float W2s[DH][D];       // [j][d] so lanes read consecutive d
    __shared__ float xs[4][RG * D];    // per-wave x rows
    __shared__ float hs[4][RG * DH];   // per-wave hidden acts

    for (int idx = threadIdx.x; idx < DH * D; idx += THREADS_AC) {
        int j = idx >> 7, k = idx & (D - 1);
        W1s[j][k] = fc1_w[idx];          // fc1_w [32][128] row-major
        W2s[j][k] = fc2_w[k * DH + j];   // fc2_w [128][32] -> transpose (k is 'd')
    }
    const int lane = threadIdx.x & 63;
    const int wv = threadIdx.x >> 6;
    const int jl = lane & 31;
    const int kb = (lane >> 5) << 6;   // half-wave: k in [0,64) or [64,128)
    const float b1r = fc1_b[jl];
    const float b20 = fc2_b[lane];
    const float b21 = fc2_b[lane + 64];
    __syncthreads();

    int chunk = (N + (int)gridDim.x - 1) / (int)gridDim.x;
    int bs = blockIdx.x * chunk;
    int be = min(N, bs + chunk);
    int rows = be - bs; if (rows < 0) rows = 0;
    int wn = (rows + 3) >> 2;          // contiguous sub-range per wave
    int rs = bs + wv * wn;
    int re = min(be, rs + wn);

    float* xw = xs[wv];
    float* hw = hs[wv];

    float acc0 = 0.f, acc1 = 0.f, acnt = 0.f;
    int cur = -1;

    for (int r0 = rs; r0 < re; r0 += RG) {
        float x0[RG], x1[RG];
        #pragma unroll
        for (int g = 0; g < RG; ++g) {
            int r = r0 + g;
            if (r < re) {
                int base = r << 7;
                x0[g] = x[base + lane];
                x1[g] = x[base + 64 + lane];
            } else { x0[g] = 0.f; x1[g] = 0.f; }
            xw[g * D + lane] = x0[g];
            xw[g * D + 64 + lane] = x1[g];
        }
        // h = W1 x : lane jl computes h[jl] partial over its half of k
        float ha[RG] = {0.f, 0.f, 0.f, 0.f};
        #pragma unroll
        for (int kk = 0; kk < 64; kk += 4) {
            float4 w = *(const float4*)&W1s[jl][kb + kk];
            #pragma unroll
            for (int g = 0; g < RG; ++g) {
                float4 xv = *(const float4*)&xw[g * D + kb + kk];
                ha[g] = fmaf(w.x, xv.x, ha[g]);
                ha[g] = fmaf(w.y, xv.y, ha[g]);
                ha[g] = fmaf(w.z, xv.z, ha[g]);
                ha[g] = fmaf(w.w, xv.w, ha[g]);
            }
        }
        #pragma unroll
        for (int g = 0; g < RG; ++g) {
            float h = ha[g] + __shfl_xor(ha[g], 32);
            h = fmaxf(h + b1r, 0.f);
            if (lane < 32) hw[g * DH + jl] = h;
        }
        // a = W2 h : lane handles d = lane and lane+64.
        // NOTE: no address-taken locals here — scalar float4 + named components
        // (round-1's float4 hv[RG] + pointer cast spilled to scratch: 6.5 GB HBM).
        float a0[RG] = {0.f,0.f,0.f,0.f}, a1[RG] = {0.f,0.f,0.f,0.f};
        #pragma unroll
        for (int jj = 0; jj < DH; jj += 4) {
            float w00 = W2s[jj + 0][lane];
            float w01 = W2s[jj + 1][lane];
            float w02 = W2s[jj + 2][lane];
            float w03 = W2s[jj + 3][lane];
            float w10 = W2s[jj + 0][lane + 64];
            float w11 = W2s[jj + 1][lane + 64];
            float w12 = W2s[jj + 2][lane + 64];
            float w13 = W2s[jj + 3][lane + 64];
            #pragma unroll
            for (int g = 0; g < RG; ++g) {
                float4 hv = *(const float4*)&hw[g * DH + jj];
                a0[g] = fmaf(w00, hv.x, a0[g]);
                a0[g] = fmaf(w01, hv.y, a0[g]);
                a0[g] = fmaf(w02, hv.z, a0[g]);
                a0[g] = fmaf(w03, hv.w, a0[g]);
                a1[g] = fmaf(w10, hv.x, a1[g]);
                a1[g] = fmaf(w11, hv.y, a1[g]);
                a1[g] = fmaf(w12, hv.z, a1[g]);
                a1[g] = fmaf(w13, hv.w, a1[g]);
            }
        }
        #pragma unroll
        for (int g = 0; g < RG; ++g) {
            int r = r0 + g;
            if (r >= re) break;                 // wave-uniform
            float t0 = fast_tanh(a0[g] + b20);
            float t1 = fast_tanh(a1[g] + b21);
            float y0 = fmaf(x0[g], t0, x0[g]);  // x*(1+tanh)
            float y1 = fmaf(x1[g], t1, x1[g]);
            int seg = batch[r];
            if (PHASE == 1) {
                float g0 = tg[(seg << 7) + lane];
                float g1 = tg[(seg << 7) + 64 + lane];
                float dot = y0 * g0 + y1 * g1;
                #pragma unroll
                for (int off = 32; off; off >>= 1) dot += __shfl_xor(dot, off);
                float coef = 1.f / (1.f + __expf(-dot));
                y0 *= coef; y1 *= coef;
            }
            if (seg != cur) {
                if (cur >= 0) {
                    atomicAdd(&dst[(cur << 7) + lane], acc0);
                    atomicAdd(&dst[(cur << 7) + 64 + lane], acc1);
                    if (PHASE == 0 && lane == 0) atomicAdd(&cnt[cur], acnt);
                }
                cur = seg; acc0 = y0; acc1 = y1; acnt = 1.f;
            } else {
                acc0 += y0; acc1 += y1; acnt += 1.f;
            }
        }
    }
    if (cur >= 0) {
        atomicAdd(&dst[(cur << 7) + lane], acc0);
        atomicAdd(&dst[(cur << 7) + 64 + lane], acc1);
        if (PHASE == 0 && lane == 0) atomicAdd(&cnt[cur], acnt);
    }
}

// tg = tanh((sums/max(cnt,1)) @ Wm), one block (128 thr) per segment row
__global__ __launch_bounds__(D, 8) void phaseB(
    const float* __restrict__ sums, const float* __restrict__ cnt,
    const float* __restrict__ Wm, float* __restrict__ tg)
{
    int b = blockIdx.x;
    int d = threadIdx.x;
    __shared__ float m[D];
    float inv = 1.f / fmaxf(cnt[b], 1.f);
    m[d] = sums[(b << 7) + d] * inv;
    __syncthreads();
    float acc = 0.f;
    #pragma unroll 8
    for (int k = 0; k < D; ++k)
        acc = fmaf(m[k], Wm[(k << 7) + d], acc);
    tg[(b << 7) + d] = fast_tanh(acc);
}

extern "C" void kernel_launch(void* const* d_in, const int* in_sizes, int n_in,
                              void* d_out, int out_size, void* d_ws, size_t ws_size,
                              hipStream_t stream) {
    const float* x     = (const float*)d_in[0];
    const int*   batch = (const int*)d_in[1];
    // d_in[2] = size scalar (B derived from out_size instead)
    const float* Wm    = (const float*)d_in[3];
    const float* fc1_w = (const float*)d_in[4];
    const float* fc1_b = (const float*)d_in[5];
    const float* fc2_w = (const float*)d_in[6];
    const float* fc2_b = (const float*)d_in[7];
    float* out = (float*)d_out;

    int N = in_sizes[0] / D;
    int B = out_size / D;

    float* sums = (float*)d_ws;          // [B,128]
    float* cnt  = sums + (size_t)B * D;  // [B]
    float* tg   = cnt + B;               // [B,128]

    hipMemsetAsync(d_ws, 0, ((size_t)B * D + B) * sizeof(float), stream);
    hipMemsetAsync(d_out, 0, (size_t)out_size * sizeof(float), stream);

    phaseAC<0><<<BLOCKS_AC, THREADS_AC, 0, stream>>>(
        x, batch, fc1_w, fc1_b, fc2_w, fc2_b, nullptr, sums, cnt, N);
    phaseB<<<B, D, 0, stream>>>(sums, cnt, Wm, tg);
    phaseAC<1><<<BLOCKS_AC, THREADS_AC, 0, stream>>>(
        x, batch, fc1_w, fc1_b, fc2_w, fc2_b, tg, out, nullptr, N);
}

// Round 3
// 3810.361 us; speedup vs baseline: 1.0965x; 1.0955x over previous
//
#include <hip/hip_runtime.h>
#include <math.h>

#define D 128
#define DH 32
#define RG 4
#define BLOCKS_AC 768
#define THREADS_AC 256

__device__ __forceinline__ float fast_tanh(float z) {
    float e = __expf(2.f * z);
    return 1.f - 2.f / (e + 1.f);
}

// Per-row tail: activation, x2, optional coef, segment-run accumulate.
// Literal G only — NO indexed locals anywhere (R1/R2 had 6.5 GB/dispatch of
// scratch traffic from an unroll-break forcing x0[]/a0[]/... into allocas).
#define ROW_EPILOGUE(G, XG0, XG1, AG0, AG1)                                   \
    {                                                                         \
        int r = r0 + (G);                                                     \
        if (r < re) { /* wave-uniform guard, no break */                      \
            float t0 = fast_tanh((AG0) + b20);                                \
            float t1 = fast_tanh((AG1) + b21);                                \
            float y0 = fmaf((XG0), t0, (XG0));                                \
            float y1 = fmaf((XG1), t1, (XG1));                                \
            int seg = batch[r];                                               \
            if (PHASE == 1) {                                                 \
                float g0 = tg[(seg << 7) + lane];                             \
                float g1 = tg[(seg << 7) + 64 + lane];                        \
                float dot = y0 * g0 + y1 * g1;                                \
                dot += __shfl_xor(dot, 32);                                   \
                dot += __shfl_xor(dot, 16);                                   \
                dot += __shfl_xor(dot, 8);                                    \
                dot += __shfl_xor(dot, 4);                                    \
                dot += __shfl_xor(dot, 2);                                    \
                dot += __shfl_xor(dot, 1);                                    \
                float coef = 1.f / (1.f + __expf(-dot));                      \
                y0 *= coef; y1 *= coef;                                       \
            }                                                                 \
            if (seg != cur) {                                                 \
                if (cur >= 0) {                                               \
                    atomicAdd(&dst[(cur << 7) + lane], acc0);                 \
                    atomicAdd(&dst[(cur << 7) + 64 + lane], acc1);            \
                    if (PHASE == 0 && lane == 0) atomicAdd(&cnt[cur], acnt);  \
                }                                                             \
                cur = seg; acc0 = y0; acc1 = y1; acnt = 1.f;                  \
            } else {                                                          \
                acc0 += y0; acc1 += y1; acnt += 1.f;                          \
            }                                                                 \
        }                                                                     \
    }

// PHASE 0: x2 -> segment sums + counts.  PHASE 1: x2, coef, coef*x2 -> out.
template <int PHASE>
__global__ __launch_bounds__(THREADS_AC, 3) void phaseAC(
    const float* __restrict__ x, const int* __restrict__ batch,
    const float* __restrict__ fc1_w, const float* __restrict__ fc1_b,
    const float* __restrict__ fc2_w, const float* __restrict__ fc2_b,
    const float* __restrict__ tg, float* __restrict__ dst,
    float* __restrict__ cnt, int N)
{
    __shared__ float W1s[DH][D + 4];   // pitch 132
    __shared__ float W2s[DH][D];       // [j][d]
    __shared__ float xs[4][RG * D];    // per-wave x rows
    __shared__ float hs[4][RG * DH];   // per-wave hidden acts

    for (int idx = threadIdx.x; idx < DH * D; idx += THREADS_AC) {
        int j = idx >> 7, k = idx & (D - 1);
        W1s[j][k] = fc1_w[idx];          // fc1_w [32][128]
        W2s[j][k] = fc2_w[k * DH + j];   // fc2_w [128][32] transposed
    }
    const int lane = threadIdx.x & 63;
    const int wv = threadIdx.x >> 6;
    const int jl = lane & 31;
    const int kb = (lane >> 5) << 6;   // half-wave: k in [0,64) or [64,128)
    const float b1r = fc1_b[jl];
    const float b20 = fc2_b[lane];
    const float b21 = fc2_b[lane + 64];
    __syncthreads();

    int chunk = (N + (int)gridDim.x - 1) / (int)gridDim.x;
    int bs = blockIdx.x * chunk;
    int be = min(N, bs + chunk);
    int rows = be - bs; if (rows < 0) rows = 0;
    int wn = (rows + 3) >> 2;
    int rs = bs + wv * wn;
    int re = min(be, rs + wn);

    float* xw = xs[wv];
    float* hw = hs[wv];

    float acc0 = 0.f, acc1 = 0.f, acnt = 0.f;
    int cur = -1;

    for (int r0 = rs; r0 < re; r0 += RG) {
        const int base = r0 << 7;
        float xa0 = x[base + lane], xa1 = x[base + 64 + lane];
        float xb0 = 0.f, xb1 = 0.f, xc0 = 0.f, xc1 = 0.f, xd0 = 0.f, xd1 = 0.f;
        if (r0 + 1 < re) { xb0 = x[base + 128 + lane]; xb1 = x[base + 192 + lane]; }
        if (r0 + 2 < re) { xc0 = x[base + 256 + lane]; xc1 = x[base + 320 + lane]; }
        if (r0 + 3 < re) { xd0 = x[base + 384 + lane]; xd1 = x[base + 448 + lane]; }
        xw[lane]           = xa0; xw[64 + lane]          = xa1;
        xw[D + lane]       = xb0; xw[D + 64 + lane]      = xb1;
        xw[2 * D + lane]   = xc0; xw[2 * D + 64 + lane]  = xc1;
        xw[3 * D + lane]   = xd0; xw[3 * D + 64 + lane]  = xd1;
        // wave-private LDS region: in-order DS pipe makes write->read safe

        // h = W1 x, lane jl computes h[jl] partial over its half of k
        float hA = 0.f, hB = 0.f, hC = 0.f, hD = 0.f;
        #pragma unroll
        for (int kk = 0; kk < 64; kk += 4) {
            const float4 w  = *(const float4*)&W1s[jl][kb + kk];
            const float4 va = *(const float4*)&xw[kb + kk];
            const float4 vb = *(const float4*)&xw[D + kb + kk];
            const float4 vc = *(const float4*)&xw[2 * D + kb + kk];
            const float4 vd = *(const float4*)&xw[3 * D + kb + kk];
            hA = fmaf(w.x, va.x, hA); hA = fmaf(w.y, va.y, hA);
            hA = fmaf(w.z, va.z, hA); hA = fmaf(w.w, va.w, hA);
            hB = fmaf(w.x, vb.x, hB); hB = fmaf(w.y, vb.y, hB);
            hB = fmaf(w.z, vb.z, hB); hB = fmaf(w.w, vb.w, hB);
            hC = fmaf(w.x, vc.x, hC); hC = fmaf(w.y, vc.y, hC);
            hC = fmaf(w.z, vc.z, hC); hC = fmaf(w.w, vc.w, hC);
            hD = fmaf(w.x, vd.x, hD); hD = fmaf(w.y, vd.y, hD);
            hD = fmaf(w.z, vd.z, hD); hD = fmaf(w.w, vd.w, hD);
        }
        {
            float h;
            h = hA + __shfl_xor(hA, 32); h = fmaxf(h + b1r, 0.f);
            if (lane < 32) hw[jl] = h;
            h = hB + __shfl_xor(hB, 32); h = fmaxf(h + b1r, 0.f);
            if (lane < 32) hw[DH + jl] = h;
            h = hC + __shfl_xor(hC, 32); h = fmaxf(h + b1r, 0.f);
            if (lane < 32) hw[2 * DH + jl] = h;
            h = hD + __shfl_xor(hD, 32); h = fmaxf(h + b1r, 0.f);
            if (lane < 32) hw[3 * DH + jl] = h;
        }

        // a = W2 h, lane handles d = lane and d = lane+64
        float aA0 = 0.f, aA1 = 0.f, aB0 = 0.f, aB1 = 0.f;
        float aC0 = 0.f, aC1 = 0.f, aD0 = 0.f, aD1 = 0.f;
        #pragma unroll
        for (int jj = 0; jj < DH; jj += 4) {
            float w00 = W2s[jj + 0][lane];
            float w01 = W2s[jj + 1][lane];
            float w02 = W2s[jj + 2][lane];
            float w03 = W2s[jj + 3][lane];
            float w10 = W2s[jj + 0][lane + 64];
            float w11 = W2s[jj + 1][lane + 64];
            float w12 = W2s[jj + 2][lane + 64];
            float w13 = W2s[jj + 3][lane + 64];
            const float4 hA4 = *(const float4*)&hw[jj];
            const float4 hB4 = *(const float4*)&hw[DH + jj];
            const float4 hC4 = *(const float4*)&hw[2 * DH + jj];
            const float4 hD4 = *(const float4*)&hw[3 * DH + jj];
            aA0 = fmaf(w00, hA4.x, aA0); aA0 = fmaf(w01, hA4.y, aA0);
            aA0 = fmaf(w02, hA4.z, aA0); aA0 = fmaf(w03, hA4.w, aA0);
            aA1 = fmaf(w10, hA4.x, aA1); aA1 = fmaf(w11, hA4.y, aA1);
            aA1 = fmaf(w12, hA4.z, aA1); aA1 = fmaf(w13, hA4.w, aA1);
            aB0 = fmaf(w00, hB4.x, aB0); aB0 = fmaf(w01, hB4.y, aB0);
            aB0 = fmaf(w02, hB4.z, aB0); aB0 = fmaf(w03, hB4.w, aB0);
            aB1 = fmaf(w10, hB4.x, aB1); aB1 = fmaf(w11, hB4.y, aB1);
            aB1 = fmaf(w12, hB4.z, aB1); aB1 = fmaf(w13, hB4.w, aB1);
            aC0 = fmaf(w00, hC4.x, aC0); aC0 = fmaf(w01, hC4.y, aC0);
            aC0 = fmaf(w02, hC4.z, aC0); aC0 = fmaf(w03, hC4.w, aC0);
            aC1 = fmaf(w10, hC4.x, aC1); aC1 = fmaf(w11, hC4.y, aC1);
            aC1 = fmaf(w12, hC4.z, aC1); aC1 = fmaf(w13, hC4.w, aC1);
            aD0 = fmaf(w00, hD4.x, aD0); aD0 = fmaf(w01, hD4.y, aD0);
            aD0 = fmaf(w02, hD4.z, aD0); aD0 = fmaf(w03, hD4.w, aD0);
            aD1 = fmaf(w10, hD4.x, aD1); aD1 = fmaf(w11, hD4.y, aD1);
            aD1 = fmaf(w12, hD4.z, aD1); aD1 = fmaf(w13, hD4.w, aD1);
        }

        ROW_EPILOGUE(0, xa0, xa1, aA0, aA1)
        ROW_EPILOGUE(1, xb0, xb1, aB0, aB1)
        ROW_EPILOGUE(2, xc0, xc1, aC0, aC1)
        ROW_EPILOGUE(3, xd0, xd1, aD0, aD1)
    }
    if (cur >= 0) {
        atomicAdd(&dst[(cur << 7) + lane], acc0);
        atomicAdd(&dst[(cur << 7) + 64 + lane], acc1);
        if (PHASE == 0 && lane == 0) atomicAdd(&cnt[cur], acnt);
    }
}

// tg = tanh((sums/max(cnt,1)) @ Wm), one block (128 thr) per segment row
__global__ __launch_bounds__(D, 8) void phaseB(
    const float* __restrict__ sums, const float* __restrict__ cnt,
    const float* __restrict__ Wm, float* __restrict__ tg)
{
    int b = blockIdx.x;
    int d = threadIdx.x;
    __shared__ float m[D];
    float inv = 1.f / fmaxf(cnt[b], 1.f);
    m[d] = sums[(b << 7) + d] * inv;
    __syncthreads();
    float acc = 0.f;
    #pragma unroll 8
    for (int k = 0; k < D; ++k)
        acc = fmaf(m[k], Wm[(k << 7) + d], acc);
    tg[(b << 7) + d] = fast_tanh(acc);
}

extern "C" void kernel_launch(void* const* d_in, const int* in_sizes, int n_in,
                              void* d_out, int out_size, void* d_ws, size_t ws_size,
                              hipStream_t stream) {
    const float* x     = (const float*)d_in[0];
    const int*   batch = (const int*)d_in[1];
    const float* Wm    = (const float*)d_in[3];
    const float* fc1_w = (const float*)d_in[4];
    const float* fc1_b = (const float*)d_in[5];
    const float* fc2_w = (const float*)d_in[6];
    const float* fc2_b = (const float*)d_in[7];
    float* out = (float*)d_out;

    int N = in_sizes[0] / D;
    int B = out_size / D;

    float* sums = (float*)d_ws;          // [B,128]
    float* cnt  = sums + (size_t)B * D;  // [B]
    float* tg   = cnt + B;               // [B,128]

    hipMemsetAsync(d_ws, 0, ((size_t)B * D + B) * sizeof(float), stream);
    hipMemsetAsync(d_out, 0, (size_t)out_size * sizeof(float), stream);

    phaseAC<0><<<BLOCKS_AC, THREADS_AC, 0, stream>>>(
        x, batch, fc1_w, fc1_b, fc2_w, fc2_b, nullptr, sums, cnt, N);
    phaseB<<<B, D, 0, stream>>>(sums, cnt, Wm, tg);
    phaseAC<1><<<BLOCKS_AC, THREADS_AC, 0, stream>>>(
        x, batch, fc1_w, fc1_b, fc2_w, fc2_b, tg, out, nullptr, N);
}

// Round 4
// 777.015 us; speedup vs baseline: 5.3771x; 4.9038x over previous
//
#include <hip/hip_runtime.h>
#include <math.h>

#define D 128
#define DH 32
#define RG 4
#define BLOCKS_AC 768
#define THREADS_AC 256

__device__ __forceinline__ float fast_tanh(float z) {
    float e = __expf(2.f * z);
    return 1.f - 2.f / (e + 1.f);
}

// Per-row tail: activation, x2, optional coef, segment-run accumulate.
// Literal G only — NO indexed locals (R1/R2 scratch lesson).
#define ROW_EPILOGUE(G, XG0, XG1, AG0, AG1)                                   \
    {                                                                         \
        int r = r0 + (G);                                                     \
        if (r < re) { /* wave-uniform guard, no break */                      \
            float t0 = fast_tanh((AG0) + b20);                                \
            float t1 = fast_tanh((AG1) + b21);                                \
            float y0 = fmaf((XG0), t0, (XG0));                                \
            float y1 = fmaf((XG1), t1, (XG1));                                \
            int seg = batch[r];                                               \
            if (PHASE == 1) {                                                 \
                float g0 = tg[(seg << 7) + lane];                             \
                float g1 = tg[(seg << 7) + 64 + lane];                        \
                float dot = y0 * g0 + y1 * g1;                                \
                dot += __shfl_xor(dot, 32);                                   \
                dot += __shfl_xor(dot, 16);                                   \
                dot += __shfl_xor(dot, 8);                                    \
                dot += __shfl_xor(dot, 4);                                    \
                dot += __shfl_xor(dot, 2);                                    \
                dot += __shfl_xor(dot, 1);                                    \
                float coef = 1.f / (1.f + __expf(-dot));                      \
                y0 *= coef; y1 *= coef;                                       \
            }                                                                 \
            if (seg != cur) {                                                 \
                if (cur >= 0) {                                               \
                    atomicAdd(&dst[(cur << 7) + lane], acc0);                 \
                    atomicAdd(&dst[(cur << 7) + 64 + lane], acc1);            \
                    if (PHASE == 0 && lane == 0) atomicAdd(&cnt[cur], acnt);  \
                }                                                             \
                cur = seg; acc0 = y0; acc1 = y1; acnt = 1.f;                  \
            } else {                                                          \
                acc0 += y0; acc1 += y1; acnt += 1.f;                          \
            }                                                                 \
        }                                                                     \
    }

// PHASE 0: x2 -> segment sums + counts.  PHASE 1: x2, coef, coef*x2 -> out.
// launch_bounds (256,2): 256-VGPR budget. R3 ran (256,3) => 170-VGPR cap and
// the fully-unrolled loops' 80 clustered ds_read_b128 results forced ~5.6 GB
// of regalloc spill traffic per dispatch. Partial unrolls bound the cluster.
template <int PHASE>
__global__ __launch_bounds__(THREADS_AC, 2) void phaseAC(
    const float* __restrict__ x, const int* __restrict__ batch,
    const float* __restrict__ fc1_w, const float* __restrict__ fc1_b,
    const float* __restrict__ fc2_w, const float* __restrict__ fc2_b,
    const float* __restrict__ tg, float* __restrict__ dst,
    float* __restrict__ cnt, int N)
{
    __shared__ float W1s[DH][D + 4];   // pitch 132
    __shared__ float W2s[DH][D];       // [j][d]
    __shared__ float xs[4][RG * D];    // per-wave x rows
    __shared__ float hs[4][RG * DH];   // per-wave hidden acts

    for (int idx = threadIdx.x; idx < DH * D; idx += THREADS_AC) {
        int j = idx >> 7, k = idx & (D - 1);
        W1s[j][k] = fc1_w[idx];          // fc1_w [32][128]
        W2s[j][k] = fc2_w[k * DH + j];   // fc2_w [128][32] transposed
    }
    const int lane = threadIdx.x & 63;
    const int wv = threadIdx.x >> 6;
    const int jl = lane & 31;
    const int kb = (lane >> 5) << 6;   // half-wave: k in [0,64) or [64,128)
    const float b1r = fc1_b[jl];
    const float b20 = fc2_b[lane];
    const float b21 = fc2_b[lane + 64];
    __syncthreads();

    int chunk = (N + (int)gridDim.x - 1) / (int)gridDim.x;
    int bs = blockIdx.x * chunk;
    int be = min(N, bs + chunk);
    int rows = be - bs; if (rows < 0) rows = 0;
    int wn = (rows + 3) >> 2;
    int rs = bs + wv * wn;
    int re = min(be, rs + wn);

    float* xw = xs[wv];
    float* hw = hs[wv];

    float acc0 = 0.f, acc1 = 0.f, acnt = 0.f;
    int cur = -1;

    for (int r0 = rs; r0 < re; r0 += RG) {
        const int base = r0 << 7;
        float xa0 = x[base + lane], xa1 = x[base + 64 + lane];
        float xb0 = 0.f, xb1 = 0.f, xc0 = 0.f, xc1 = 0.f, xd0 = 0.f, xd1 = 0.f;
        if (r0 + 1 < re) { xb0 = x[base + 128 + lane]; xb1 = x[base + 192 + lane]; }
        if (r0 + 2 < re) { xc0 = x[base + 256 + lane]; xc1 = x[base + 320 + lane]; }
        if (r0 + 3 < re) { xd0 = x[base + 384 + lane]; xd1 = x[base + 448 + lane]; }
        xw[lane]           = xa0; xw[64 + lane]          = xa1;
        xw[D + lane]       = xb0; xw[D + 64 + lane]      = xb1;
        xw[2 * D + lane]   = xc0; xw[2 * D + 64 + lane]  = xc1;
        xw[3 * D + lane]   = xd0; xw[3 * D + 64 + lane]  = xd1;
        // wave-private LDS region: in-order DS pipe makes write->read safe

        // h = W1 x, lane jl computes h[jl] partial over its half of k.
        // PARTIAL unroll: bounds the live ds_read cluster (spill control).
        float hA = 0.f, hB = 0.f, hC = 0.f, hD = 0.f;
        #pragma unroll 2
        for (int kk = 0; kk < 64; kk += 4) {
            const float4 w  = *(const float4*)&W1s[jl][kb + kk];
            const float4 va = *(const float4*)&xw[kb + kk];
            const float4 vb = *(const float4*)&xw[D + kb + kk];
            const float4 vc = *(const float4*)&xw[2 * D + kb + kk];
            const float4 vd = *(const float4*)&xw[3 * D + kb + kk];
            hA = fmaf(w.x, va.x, hA); hA = fmaf(w.y, va.y, hA);
            hA = fmaf(w.z, va.z, hA); hA = fmaf(w.w, va.w, hA);
            hB = fmaf(w.x, vb.x, hB); hB = fmaf(w.y, vb.y, hB);
            hB = fmaf(w.z, vb.z, hB); hB = fmaf(w.w, vb.w, hB);
            hC = fmaf(w.x, vc.x, hC); hC = fmaf(w.y, vc.y, hC);
            hC = fmaf(w.z, vc.z, hC); hC = fmaf(w.w, vc.w, hC);
            hD = fmaf(w.x, vd.x, hD); hD = fmaf(w.y, vd.y, hD);
            hD = fmaf(w.z, vd.z, hD); hD = fmaf(w.w, vd.w, hD);
        }
        {
            float h;
            h = hA + __shfl_xor(hA, 32); h = fmaxf(h + b1r, 0.f);
            if (lane < 32) hw[jl] = h;
            h = hB + __shfl_xor(hB, 32); h = fmaxf(h + b1r, 0.f);
            if (lane < 32) hw[DH + jl] = h;
            h = hC + __shfl_xor(hC, 32); h = fmaxf(h + b1r, 0.f);
            if (lane < 32) hw[2 * DH + jl] = h;
            h = hD + __shfl_xor(hD, 32); h = fmaxf(h + b1r, 0.f);
            if (lane < 32) hw[3 * DH + jl] = h;
        }

        // a = W2 h, lane handles d = lane and d = lane+64
        float aA0 = 0.f, aA1 = 0.f, aB0 = 0.f, aB1 = 0.f;
        float aC0 = 0.f, aC1 = 0.f, aD0 = 0.f, aD1 = 0.f;
        #pragma unroll 2
        for (int jj = 0; jj < DH; jj += 4) {
            float w00 = W2s[jj + 0][lane];
            float w01 = W2s[jj + 1][lane];
            float w02 = W2s[jj + 2][lane];
            float w03 = W2s[jj + 3][lane];
            float w10 = W2s[jj + 0][lane + 64];
            float w11 = W2s[jj + 1][lane + 64];
            float w12 = W2s[jj + 2][lane + 64];
            float w13 = W2s[jj + 3][lane + 64];
            const float4 hA4 = *(const float4*)&hw[jj];
            const float4 hB4 = *(const float4*)&hw[DH + jj];
            const float4 hC4 = *(const float4*)&hw[2 * DH + jj];
            const float4 hD4 = *(const float4*)&hw[3 * DH + jj];
            aA0 = fmaf(w00, hA4.x, aA0); aA0 = fmaf(w01, hA4.y, aA0);
            aA0 = fmaf(w02, hA4.z, aA0); aA0 = fmaf(w03, hA4.w, aA0);
            aA1 = fmaf(w10, hA4.x, aA1); aA1 = fmaf(w11, hA4.y, aA1);
            aA1 = fmaf(w12, hA4.z, aA1); aA1 = fmaf(w13, hA4.w, aA1);
            aB0 = fmaf(w00, hB4.x, aB0); aB0 = fmaf(w01, hB4.y, aB0);
            aB0 = fmaf(w02, hB4.z, aB0); aB0 = fmaf(w03, hB4.w, aB0);
            aB1 = fmaf(w10, hB4.x, aB1); aB1 = fmaf(w11, hB4.y, aB1);
            aB1 = fmaf(w12, hB4.z, aB1); aB1 = fmaf(w13, hB4.w, aB1);
            aC0 = fmaf(w00, hC4.x, aC0); aC0 = fmaf(w01, hC4.y, aC0);
            aC0 = fmaf(w02, hC4.z, aC0); aC0 = fmaf(w03, hC4.w, aC0);
            aC1 = fmaf(w10, hC4.x, aC1); aC1 = fmaf(w11, hC4.y, aC1);
            aC1 = fmaf(w12, hC4.z, aC1); aC1 = fmaf(w13, hC4.w, aC1);
            aD0 = fmaf(w00, hD4.x, aD0); aD0 = fmaf(w01, hD4.y, aD0);
            aD0 = fmaf(w02, hD4.z, aD0); aD0 = fmaf(w03, hD4.w, aD0);
            aD1 = fmaf(w10, hD4.x, aD1); aD1 = fmaf(w11, hD4.y, aD1);
            aD1 = fmaf(w12, hD4.z, aD1); aD1 = fmaf(w13, hD4.w, aD1);
        }

        ROW_EPILOGUE(0, xa0, xa1, aA0, aA1)
        ROW_EPILOGUE(1, xb0, xb1, aB0, aB1)
        ROW_EPILOGUE(2, xc0, xc1, aC0, aC1)
        ROW_EPILOGUE(3, xd0, xd1, aD0, aD1)
    }
    if (cur >= 0) {
        atomicAdd(&dst[(cur << 7) + lane], acc0);
        atomicAdd(&dst[(cur << 7) + 64 + lane], acc1);
        if (PHASE == 0 && lane == 0) atomicAdd(&cnt[cur], acnt);
    }
}

// tg = tanh((sums/max(cnt,1)) @ Wm), one block (128 thr) per segment row
__global__ __launch_bounds__(D, 8) void phaseB(
    const float* __restrict__ sums, const float* __restrict__ cnt,
    const float* __restrict__ Wm, float* __restrict__ tg)
{
    int b = blockIdx.x;
    int d = threadIdx.x;
    __shared__ float m[D];
    float inv = 1.f / fmaxf(cnt[b], 1.f);
    m[d] = sums[(b << 7) + d] * inv;
    __syncthreads();
    float acc = 0.f;
    #pragma unroll 8
    for (int k = 0; k < D; ++k)
        acc = fmaf(m[k], Wm[(k << 7) + d], acc);
    tg[(b << 7) + d] = fast_tanh(acc);
}

extern "C" void kernel_launch(void* const* d_in, const int* in_sizes, int n_in,
                              void* d_out, int out_size, void* d_ws, size_t ws_size,
                              hipStream_t stream) {
    const float* x     = (const float*)d_in[0];
    const int*   batch = (const int*)d_in[1];
    const float* Wm    = (const float*)d_in[3];
    const float* fc1_w = (const float*)d_in[4];
    const float* fc1_b = (const float*)d_in[5];
    const float* fc2_w = (const float*)d_in[6];
    const float* fc2_b = (const float*)d_in[7];
    float* out = (float*)d_out;

    int N = in_sizes[0] / D;
    int B = out_size / D;

    float* sums = (float*)d_ws;          // [B,128]
    float* cnt  = sums + (size_t)B * D;  // [B]
    float* tg   = cnt + B;               // [B,128]

    hipMemsetAsync(d_ws, 0, ((size_t)B * D + B) * sizeof(float), stream);
    hipMemsetAsync(d_out, 0, (size_t)out_size * sizeof(float), stream);

    phaseAC<0><<<BLOCKS_AC, THREADS_AC, 0, stream>>>(
        x, batch, fc1_w, fc1_b, fc2_w, fc2_b, nullptr, sums, cnt, N);
    phaseB<<<B, D, 0, stream>>>(sums, cnt, Wm, tg);
    phaseAC<1><<<BLOCKS_AC, THREADS_AC, 0, stream>>>(
        x, batch, fc1_w, fc1_b, fc2_w, fc2_b, tg, out, nullptr, N);
}

// Round 5
// 482.347 us; speedup vs baseline: 8.6620x; 1.6109x over previous
//
#include <hip/hip_runtime.h>
#include <math.h>

#define D 128
#define BLOCKS_AC 768
#define THREADS_AC 256

typedef short s8v __attribute__((ext_vector_type(8)));
typedef float f4v __attribute__((ext_vector_type(4)));

__device__ __forceinline__ float fast_tanh(float z) {
    float e = __expf(2.f * z);
    return 1.f - 2.f / (e + 1.f);
}
__device__ __forceinline__ unsigned short f2bf(float f) {
    union { float f; unsigned u; } v; v.f = f;
    unsigned r = v.u + 0x7FFFu + ((v.u >> 16) & 1u);
    return (unsigned short)(r >> 16);
}
__device__ __forceinline__ float bf2f(unsigned short h) {
    union { unsigned u; float f; } v; v.u = ((unsigned)h) << 16;
    return v.f;
}

// Epilogue for one C-row-group register RG_ (literal 0..3).
// C/D layout (m89-verified): col = lane&15 (+16*tile), row = quad*4 + reg.
#define EPI(RG_)                                                              \
    {                                                                         \
        int r = R + quad * 4 + RG_;                                           \
        int seg = batch[r];                                                   \
        float yv[8];                                                          \
        _Pragma("unroll")                                                     \
        for (int t = 0; t < 8; ++t) {                                         \
            float xf = bf2f(xw[(quad * 4 + RG_) * 136 + m15 + 16 * t]);       \
            float z = af[t][RG_] + b2l[t];                                    \
            yv[t] = xf * (1.f + fast_tanh(z));                                \
        }                                                                     \
        if (PHASE == 1) {                                                     \
            float dot = 0.f;                                                  \
            _Pragma("unroll")                                                 \
            for (int t = 0; t < 8; ++t)                                       \
                dot = fmaf(yv[t], tg[seg * 128 + m15 + 16 * t], dot);         \
            dot += __shfl_xor(dot, 1);                                        \
            dot += __shfl_xor(dot, 2);                                        \
            dot += __shfl_xor(dot, 4);                                        \
            dot += __shfl_xor(dot, 8);                                        \
            float coef = 1.f / (1.f + __expf(-dot));                          \
            _Pragma("unroll")                                                 \
            for (int t = 0; t < 8; ++t) yv[t] *= coef;                        \
        }                                                                     \
        if (seg != cur) {                                                     \
            if (cur >= 0) {                                                   \
                _Pragma("unroll")                                             \
                for (int t = 0; t < 8; ++t)                                   \
                    atomicAdd(&dst[cur * 128 + m15 + 16 * t], acc[t]);        \
                if (PHASE == 0 && m15 == 0) atomicAdd(&cnt[cur], acnt);       \
            }                                                                 \
            cur = seg;                                                        \
            _Pragma("unroll")                                                 \
            for (int t = 0; t < 8; ++t) acc[t] = yv[t];                       \
            acnt = 1.f;                                                       \
        } else {                                                              \
            _Pragma("unroll")                                                 \
            for (int t = 0; t < 8; ++t) acc[t] += yv[t];                      \
            acnt += 1.f;                                                      \
        }                                                                     \
    }

// PHASE 0: x2 -> segment sums + counts.  PHASE 1: coef*x2 -> out.
// MFMA 16x16x32 bf16; all weight fragments live in registers; per-wave
// 16-row tiles; no __syncthreads (wave-private LDS regions, in-order DS).
template <int PHASE>
__global__ __launch_bounds__(THREADS_AC, 2) void phaseAC(
    const float* __restrict__ x, const int* __restrict__ batch,
    const float* __restrict__ fc1_w, const float* __restrict__ fc1_b,
    const float* __restrict__ fc2_w, const float* __restrict__ fc2_b,
    const float* __restrict__ tg, float* __restrict__ dst,
    float* __restrict__ cnt, int N)
{
    __shared__ unsigned short xbf[4][16 * 136]; // bf16 x rows, pitch 136 (2-way max)
    __shared__ float hbuf[4][16 * 36];          // f32 hidden, pitch 36

    const int lane = threadIdx.x & 63;
    const int wv = threadIdx.x >> 6;
    const int m15 = lane & 15;
    const int quad = lane >> 4;

    // --- Preload weight B-fragments into registers (loop-invariant) ---
    // B layout: n = lane&15 (+16*tile), k = quad*8 + j (j=0..7 consecutive).
    s8v B1[2][4]; // GEMM1: B1[k][n] = fc1_w[n][k], n-tiles 0..1, k-chunks 0..3
    #pragma unroll
    for (int t = 0; t < 2; ++t)
        #pragma unroll
        for (int kc = 0; kc < 4; ++kc) {
            const float* p = fc1_w + (16 * t + m15) * 128 + kc * 32 + quad * 8;
            float4 w0 = *(const float4*)p;
            float4 w1 = *(const float4*)(p + 4);
            s8v f;
            f[0] = (short)f2bf(w0.x); f[1] = (short)f2bf(w0.y);
            f[2] = (short)f2bf(w0.z); f[3] = (short)f2bf(w0.w);
            f[4] = (short)f2bf(w1.x); f[5] = (short)f2bf(w1.y);
            f[6] = (short)f2bf(w1.z); f[7] = (short)f2bf(w1.w);
            B1[t][kc] = f;
        }
    s8v B2[8]; // GEMM2: B2[k][n] = fc2_w[n][k], n-tiles 0..7, K=32 single chunk
    #pragma unroll
    for (int t = 0; t < 8; ++t) {
        const float* p = fc2_w + (16 * t + m15) * 32 + quad * 8;
        float4 w0 = *(const float4*)p;
        float4 w1 = *(const float4*)(p + 4);
        s8v f;
        f[0] = (short)f2bf(w0.x); f[1] = (short)f2bf(w0.y);
        f[2] = (short)f2bf(w0.z); f[3] = (short)f2bf(w0.w);
        f[4] = (short)f2bf(w1.x); f[5] = (short)f2bf(w1.y);
        f[6] = (short)f2bf(w1.z); f[7] = (short)f2bf(w1.w);
        B2[t] = f;
    }
    float b1l[2], b2l[8];
    #pragma unroll
    for (int t = 0; t < 2; ++t) b1l[t] = fc1_b[m15 + 16 * t];
    #pragma unroll
    for (int t = 0; t < 8; ++t) b2l[t] = fc2_b[m15 + 16 * t];

    // --- Row-range assignment: contiguous 16-row blocks per wave ---
    const int total16 = N >> 4;                 // N = 500000 is 16-divisible
    const int nw = BLOCKS_AC * 4;
    const int gw = blockIdx.x * 4 + wv;
    const int wpb = (total16 + nw - 1) / nw;
    const int b0 = gw * wpb;
    const int b1e = min(total16, b0 + wpb);

    unsigned short* xw = xbf[wv];
    float* hw = hbuf[wv];

    float acc[8];
    #pragma unroll
    for (int t = 0; t < 8; ++t) acc[t] = 0.f;
    int cur = -1;
    float acnt = 0.f;
    const f4v z4 = {0.f, 0.f, 0.f, 0.f};

    for (int b = b0; b < b1e; ++b) {
        const int R = b << 4;
        const float* xp = x + R * 128;
        // stage 16 rows of x as bf16: coalesced 1KB global reads
        #pragma unroll
        for (int u = 0; u < 8; ++u) {
            float4 v = *(const float4*)(xp + u * 256 + lane * 4);
            unsigned lo = (unsigned)f2bf(v.x) | ((unsigned)f2bf(v.y) << 16);
            unsigned hi = (unsigned)f2bf(v.z) | ((unsigned)f2bf(v.w) << 16);
            int row = 2 * u + (lane >> 5);
            int col = (lane & 31) * 4;
            uint2 pk; pk.x = lo; pk.y = hi;
            *(uint2*)&xw[row * 136 + col] = pk;
        }
        // A-fragments of x: A[m=lane&15][k=quad*8+j], 4 K-chunks
        s8v ax[4];
        #pragma unroll
        for (int kc = 0; kc < 4; ++kc)
            ax[kc] = *(const s8v*)&xw[m15 * 136 + kc * 32 + quad * 8];
        // GEMM1: h[16][32] = x @ W1^T
        f4v accH[2];
        accH[0] = z4; accH[1] = z4;
        #pragma unroll
        for (int kc = 0; kc < 4; ++kc) {
            accH[0] = __builtin_amdgcn_mfma_f32_16x16x32_bf16(ax[kc], B1[0][kc], accH[0], 0, 0, 0);
            accH[1] = __builtin_amdgcn_mfma_f32_16x16x32_bf16(ax[kc], B1[1][kc], accH[1], 0, 0, 0);
        }
        // bias + ReLU, stage h to LDS (f32, pitch 36)
        #pragma unroll
        for (int t = 0; t < 2; ++t)
            #pragma unroll
            for (int rg = 0; rg < 4; ++rg) {
                float hv = fmaxf(accH[t][rg] + b1l[t], 0.f);
                hw[(quad * 4 + rg) * 36 + m15 + 16 * t] = hv;
            }
        // A-fragment of h: 8 consecutive f32 -> bf16
        const f4v h0 = *(const f4v*)&hw[m15 * 36 + quad * 8];
        const f4v h1 = *(const f4v*)&hw[m15 * 36 + quad * 8 + 4];
        s8v ah;
        ah[0] = (short)f2bf(h0[0]); ah[1] = (short)f2bf(h0[1]);
        ah[2] = (short)f2bf(h0[2]); ah[3] = (short)f2bf(h0[3]);
        ah[4] = (short)f2bf(h1[0]); ah[5] = (short)f2bf(h1[1]);
        ah[6] = (short)f2bf(h1[2]); ah[7] = (short)f2bf(h1[3]);
        // GEMM2: a[16][128] = h @ W2^T, 8 n-tiles
        f4v af[8];
        #pragma unroll
        for (int t = 0; t < 8; ++t)
            af[t] = __builtin_amdgcn_mfma_f32_16x16x32_bf16(ah, B2[t], z4, 0, 0, 0);

        EPI(0) EPI(1) EPI(2) EPI(3)
    }
    if (cur >= 0) {
        #pragma unroll
        for (int t = 0; t < 8; ++t)
            atomicAdd(&dst[cur * 128 + m15 + 16 * t], acc[t]);
        if (PHASE == 0 && m15 == 0) atomicAdd(&cnt[cur], acnt);
    }
}

// tg = tanh((sums/max(cnt,1)) @ Wm), one block (128 thr) per segment row
__global__ __launch_bounds__(D, 8) void phaseB(
    const float* __restrict__ sums, const float* __restrict__ cnt,
    const float* __restrict__ Wm, float* __restrict__ tg)
{
    int b = blockIdx.x;
    int d = threadIdx.x;
    __shared__ float m[D];
    float inv = 1.f / fmaxf(cnt[b], 1.f);
    m[d] = sums[(b << 7) + d] * inv;
    __syncthreads();
    float acc = 0.f;
    #pragma unroll 8
    for (int k = 0; k < D; ++k)
        acc = fmaf(m[k], Wm[(k << 7) + d], acc);
    tg[(b << 7) + d] = fast_tanh(acc);
}

extern "C" void kernel_launch(void* const* d_in, const int* in_sizes, int n_in,
                              void* d_out, int out_size, void* d_ws, size_t ws_size,
                              hipStream_t stream) {
    const float* x     = (const float*)d_in[0];
    const int*   batch = (const int*)d_in[1];
    const float* Wm    = (const float*)d_in[3];
    const float* fc1_w = (const float*)d_in[4];
    const float* fc1_b = (const float*)d_in[5];
    const float* fc2_w = (const float*)d_in[6];
    const float* fc2_b = (const float*)d_in[7];
    float* out = (float*)d_out;

    int N = in_sizes[0] / D;
    int B = out_size / D;

    float* sums = (float*)d_ws;          // [B,128]
    float* cnt  = sums + (size_t)B * D;  // [B]
    float* tg   = cnt + B;               // [B,128]

    hipMemsetAsync(d_ws, 0, ((size_t)B * D + B) * sizeof(float), stream);
    hipMemsetAsync(d_out, 0, (size_t)out_size * sizeof(float), stream);

    phaseAC<0><<<BLOCKS_AC, THREADS_AC, 0, stream>>>(
        x, batch, fc1_w, fc1_b, fc2_w, fc2_b, nullptr, sums, cnt, N);
    phaseB<<<B, D, 0, stream>>>(sums, cnt, Wm, tg);
    phaseAC<1><<<BLOCKS_AC, THREADS_AC, 0, stream>>>(
        x, batch, fc1_w, fc1_b, fc2_w, fc2_b, tg, out, nullptr, N);
}